// Round 1
// baseline (1871.564 us; speedup 1.0000x reference)
//
#include <hip/hip_runtime.h>
#include <math.h>

// Problem constants (from reference): T=1024, D=1024, H=2048, E=32, K=2
#define T_TOK 1024
#define D_DIM 1024
#define H_DIM 2048
#define E_NUM 32
#define K_TOP 2
#define NPAIR (T_TOK * K_TOP)   // 2048

// ---------------- bucketing: group (t,k) pairs by expert ----------------
// ws layout:
//   offs    : (E+1) ints  at ws + 0
//   buckets : NPAIR ints  at ws + 256
//   inter   : NPAIR*H floats at ws + 16384  (16 MB)
__global__ void bucket_kernel(const int* __restrict__ idx,
                              int* __restrict__ offs,
                              int* __restrict__ buckets) {
    __shared__ int cnt[E_NUM];
    __shared__ int cur[E_NUM];
    const int tid = threadIdx.x;            // 1024 threads, 2 pairs each
    if (tid < E_NUM) cnt[tid] = 0;
    __syncthreads();
    const int p0 = tid * 2, p1 = tid * 2 + 1;
    const int e0 = idx[p0], e1 = idx[p1];
    atomicAdd(&cnt[e0], 1);
    atomicAdd(&cnt[e1], 1);
    __syncthreads();
    if (tid == 0) {
        int acc = 0;
        for (int e = 0; e < E_NUM; e++) { offs[e] = acc; cur[e] = acc; acc += cnt[e]; }
        offs[E_NUM] = acc;
    }
    __syncthreads();
    const int q0 = atomicAdd(&cur[e0], 1);
    buckets[q0] = p0;
    const int q1 = atomicAdd(&cur[e1], 1);
    buckets[q1] = p1;
}

// ---------------- stage 1: gate/up GEMM + silu*up -> inter ----------------
// Grid: (H/HT1, E). Block 256. Per block: HT1 h-outputs (gate AND up) for all
// tokens of expert e, looped in M-chunks of MT1.
constexpr int MT1 = 96;   // token tile (avg n=64, P(n>96)~0; loop handles any n)
constexpr int HT1 = 32;   // h outputs per block
constexpr int KC1 = 32;   // D chunk

__global__ __launch_bounds__(256) void stage1_kernel(
    const float* __restrict__ x, const float* __restrict__ Wgu,
    const int* __restrict__ offs, const int* __restrict__ buckets,
    float* __restrict__ inter) {
    const int e = blockIdx.y;
    const int h0 = blockIdx.x * HT1;
    const int start = offs[e];
    const int n = offs[e + 1] - start;
    if (n <= 0) return;

    // transposed LDS tiles, padded for aligned vector reads + bank spread
    __shared__ float Xs[KC1][MT1 + 2];        // [32][98]
    __shared__ float Ws[2][KC1][HT1 + 2];     // [2][32][34]

    const int tid = threadIdx.x;
    const int tx = tid & 15;                  // 2 h per thread
    const int ty = tid >> 4;                  // 6 tokens per thread
    const float* Wbase = Wgu + (size_t)e * 2 * H_DIM * D_DIM;

    for (int m0 = 0; m0 < n; m0 += MT1) {
        float acc[6][2][2];                   // [tok][h][gate/up]
        #pragma unroll
        for (int j = 0; j < 6; j++)
            #pragma unroll
            for (int hh = 0; hh < 2; hh++) { acc[j][hh][0] = 0.f; acc[j][hh][1] = 0.f; }

        for (int d0 = 0; d0 < D_DIM; d0 += KC1) {
            __syncthreads();
            // load X tile: 96 rows x 32 d -> transposed Xs[d][row]
            #pragma unroll
            for (int i = 0; i < 12; i++) {
                const int id = tid + i * 256;
                const int r = id >> 5, c = id & 31;
                float v = 0.f;
                const int m = m0 + r;
                if (m < n) {
                    const int pair = buckets[start + m];
                    const int t = pair >> 1;          // K_TOP = 2
                    v = x[(size_t)t * D_DIM + d0 + c];
                }
                Xs[c][r] = v;
            }
            // load W tile: (2, 32 h, 32 d) -> transposed Ws[g][d][h]
            #pragma unroll
            for (int i = 0; i < 8; i++) {
                const int id = tid + i * 256;
                const int g = id >> 10, h = (id >> 5) & 31, c = id & 31;
                Ws[g][c][h] = Wbase[((size_t)g * H_DIM + h0 + h) * D_DIM + d0 + c];
            }
            __syncthreads();
            #pragma unroll
            for (int d = 0; d < KC1; d++) {
                float xv[6], wg[2], wu[2];
                #pragma unroll
                for (int j = 0; j < 6; j++) xv[j] = Xs[d][ty * 6 + j];
                #pragma unroll
                for (int hh = 0; hh < 2; hh++) {
                    wg[hh] = Ws[0][d][tx * 2 + hh];
                    wu[hh] = Ws[1][d][tx * 2 + hh];
                }
                #pragma unroll
                for (int j = 0; j < 6; j++)
                    #pragma unroll
                    for (int hh = 0; hh < 2; hh++) {
                        acc[j][hh][0] += xv[j] * wg[hh];
                        acc[j][hh][1] += xv[j] * wu[hh];
                    }
            }
        }
        // epilogue: silu(gate)*up -> inter
        #pragma unroll
        for (int j = 0; j < 6; j++) {
            const int m = m0 + ty * 6 + j;
            if (m < n) {
                float* dst = inter + (size_t)(start + m) * H_DIM + h0 + tx * 2;
                #pragma unroll
                for (int hh = 0; hh < 2; hh++) {
                    const float g = acc[j][hh][0];
                    const float u = acc[j][hh][1];
                    const float s = g / (1.f + __expf(-g));
                    dst[hh] = s * u;
                }
            }
        }
    }
}

// ---------------- stage 2: down GEMM -> scatter to out ----------------
// Grid: (D/NT2, E). Block 256.
constexpr int MT2 = 96;   // token tile
constexpr int NT2 = 64;   // d outputs per block (4 per thread -> float4 stores)
constexpr int KC2 = 32;   // H chunk

__global__ __launch_bounds__(256) void stage2_kernel(
    const float* __restrict__ inter, const float* __restrict__ Wd,
    const int* __restrict__ offs, const int* __restrict__ buckets,
    float* __restrict__ out) {
    const int e = blockIdx.y;
    const int d0 = blockIdx.x * NT2;
    const int start = offs[e];
    const int n = offs[e + 1] - start;
    if (n <= 0) return;

    __shared__ float Is[KC2][MT2 + 2];        // [32][98]
    __shared__ float Ws2[KC2][NT2 + 4];       // [32][68] (b128-aligned reads)

    const int tid = threadIdx.x;
    const int tx = tid & 15;                  // 4 d-outputs per thread
    const int ty = tid >> 4;                  // 6 tokens per thread
    const float* Wbase = Wd + (size_t)e * D_DIM * H_DIM;

    for (int m0 = 0; m0 < n; m0 += MT2) {
        float acc[6][4];
        #pragma unroll
        for (int j = 0; j < 6; j++)
            #pragma unroll
            for (int dd = 0; dd < 4; dd++) acc[j][dd] = 0.f;

        for (int h0 = 0; h0 < H_DIM; h0 += KC2) {
            __syncthreads();
            #pragma unroll
            for (int i = 0; i < 12; i++) {
                const int id = tid + i * 256;
                const int r = id >> 5, c = id & 31;
                float v = 0.f;
                if (m0 + r < n) v = inter[(size_t)(start + m0 + r) * H_DIM + h0 + c];
                Is[c][r] = v;
            }
            #pragma unroll
            for (int i = 0; i < 8; i++) {
                const int id = tid + i * 256;
                const int r = id >> 5, c = id & 31;   // r: 0..63 d-rows
                Ws2[c][r] = Wbase[(size_t)(d0 + r) * H_DIM + h0 + c];
            }
            __syncthreads();
            #pragma unroll
            for (int h = 0; h < KC2; h++) {
                float xv[6], wv[4];
                #pragma unroll
                for (int j = 0; j < 6; j++) xv[j] = Is[h][ty * 6 + j];
                #pragma unroll
                for (int dd = 0; dd < 4; dd++) wv[dd] = Ws2[h][tx * 4 + dd];
                #pragma unroll
                for (int j = 0; j < 6; j++)
                    #pragma unroll
                    for (int dd = 0; dd < 4; dd++) acc[j][dd] += xv[j] * wv[dd];
            }
        }
        // epilogue: scatter rows to out[pair]
        #pragma unroll
        for (int j = 0; j < 6; j++) {
            const int m = m0 + ty * 6 + j;
            if (m < n) {
                const int pair = buckets[start + m];
                float* dst = out + (size_t)pair * D_DIM + d0 + tx * 4;
                #pragma unroll
                for (int dd = 0; dd < 4; dd++) dst[dd] = acc[j][dd];
            }
        }
    }
}

extern "C" void kernel_launch(void* const* d_in, const int* in_sizes, int n_in,
                              void* d_out, int out_size, void* d_ws, size_t ws_size,
                              hipStream_t stream) {
    const float* x   = (const float*)d_in[0];
    const int*   idx = (const int*)d_in[1];
    const float* Wgu = (const float*)d_in[2];
    const float* Wd  = (const float*)d_in[3];
    float* out = (float*)d_out;

    char* ws = (char*)d_ws;
    int*   offs    = (int*)ws;                 // 33 ints
    int*   buckets = (int*)(ws + 256);         // 2048 ints
    float* inter   = (float*)(ws + 16384);     // 2048 x 2048 floats = 16 MB

    bucket_kernel<<<dim3(1), dim3(1024), 0, stream>>>(idx, offs, buckets);

    dim3 g1(H_DIM / HT1, E_NUM);               // (64, 32)
    stage1_kernel<<<g1, dim3(256), 0, stream>>>(x, Wgu, offs, buckets, inter);

    dim3 g2(D_DIM / NT2, E_NUM);               // (16, 32)
    stage2_kernel<<<g2, dim3(256), 0, stream>>>(inter, Wd, offs, buckets, out);
}